// Round 3
// baseline (117.361 us; speedup 1.0000x reference)
//
#include <hip/hip_runtime.h>

// RelativeMultiHeadSelfAttention: B=16, S=1024, C=256, H=8 heads, D=32 head_dim
// prep (casts + bias gather, pre-scaled by INV_LN2) -> QKV GEMM (bf16 MFMA, q
// pre-scaled by SCALE*INV_LN2) -> V transpose -> fused attention (bias as MFMA
// C-init, ones-MFMA row sums, cvt_pk P conversion) -> merge GEMM (f32 out)

typedef __attribute__((ext_vector_type(8))) short bf16x8;
typedef __attribute__((ext_vector_type(4))) float f32x4;

#define INV_LN2 1.44269504088896340736f

__device__ __forceinline__ unsigned short f2bf(float f) {
  union { float f; unsigned u; } v; v.f = f;
  unsigned r = v.u + 0x7fffu + ((v.u >> 16) & 1u);   // RNE
  return (unsigned short)(r >> 16);
}
__device__ __forceinline__ float bf2f(unsigned short h) {
  union { unsigned u; float f; } v; v.u = ((unsigned)h) << 16;
  return v.f;
}

// ---------------- prep: casts + bias gather ----------------
__global__ __launch_bounds__(256) void prep_kernel(
    const float* __restrict__ x, const float* __restrict__ wq,
    const float* __restrict__ wm, const float* __restrict__ tab,
    const int* __restrict__ idx,
    unsigned short* __restrict__ xb, unsigned short* __restrict__ wqb,
    unsigned short* __restrict__ wmb, unsigned short* __restrict__ biasb) {
  const long NX = 1048576, NW1 = 49152, NW2 = 16384, NB = 262144;
  long u = (long)blockIdx.x * 256 + threadIdx.x;
  if (u < NX) {
    float4 v = ((const float4*)x)[u];
    ushort4 o; o.x = f2bf(v.x); o.y = f2bf(v.y); o.z = f2bf(v.z); o.w = f2bf(v.w);
    ((ushort4*)xb)[u] = o;
  } else if (u < NX + NW1) {
    long t = u - NX;
    float4 v = ((const float4*)wq)[t];
    ushort4 o; o.x = f2bf(v.x); o.y = f2bf(v.y); o.z = f2bf(v.z); o.w = f2bf(v.w);
    ((ushort4*)wqb)[t] = o;
  } else if (u < NX + NW1 + NW2) {
    long t = u - NX - NW1;
    float4 v = ((const float4*)wm)[t];
    ushort4 o; o.x = f2bf(v.x); o.y = f2bf(v.y); o.z = f2bf(v.z); o.w = f2bf(v.w);
    ((ushort4*)wmb)[t] = o;
  } else if (u < NX + NW1 + NW2 + NB) {
    long t = u - NX - NW1 - NW2;
    int4 iv = ((const int4*)idx)[t];
    ushort4 o;
    o.x = f2bf(tab[(long)iv.x * 8] * INV_LN2);
    o.y = f2bf(tab[(long)iv.y * 8] * INV_LN2);
    o.z = f2bf(tab[(long)iv.z * 8] * INV_LN2);
    o.w = f2bf(tab[(long)iv.w * 8] * INV_LN2);
    ((ushort4*)biasb)[t] = o;
  }
}

// ---------------- GEMM (QKV / merge) ----------------
// C[m,n] = sum_k A[m,k]*Bw[n,k] (+ bias[n]); padded LDS [128][40] (rows 80B,
// 16B-aligned).
template <int MODE>
__global__ __launch_bounds__(256) void gemm_k(
    const unsigned short* __restrict__ A, const unsigned short* __restrict__ Bw,
    const float* __restrict__ bias,
    unsigned short* __restrict__ q_ws, unsigned short* __restrict__ k_ws,
    unsigned short* __restrict__ v_ws, float* __restrict__ out) {
  __shared__ __align__(16) unsigned short As[128 * 40];
  __shared__ __align__(16) unsigned short Bs[128 * 40];
  const int tid = threadIdx.x;
  const int lane = tid & 63, wid = tid >> 6;
  const int wm = wid >> 1, wn = wid & 1;
  const int li = lane & 15, g = lane >> 4;
  const int m0 = blockIdx.y * 128;
  const int n0 = blockIdx.x * 128;
  f32x4 acc[4][4] = {};
  const int srow = tid >> 2, sg = tid & 3;
  const unsigned short* Ag = A + (long)(m0 + srow) * 256 + sg * 8;
  const unsigned short* Bg = Bw + (long)(n0 + srow) * 256 + sg * 8;

  for (int kt = 0; kt < 8; ++kt) {
    const int k0 = kt * 32;
    bf16x8 a0 = *(const bf16x8*)(Ag + k0);
    bf16x8 a1 = *(const bf16x8*)(Ag + 64 * 256 + k0);
    bf16x8 b0 = *(const bf16x8*)(Bg + k0);
    bf16x8 b1 = *(const bf16x8*)(Bg + 64 * 256 + k0);
    __syncthreads();
    *(bf16x8*)(As + srow * 40 + sg * 8) = a0;
    *(bf16x8*)(As + (srow + 64) * 40 + sg * 8) = a1;
    *(bf16x8*)(Bs + srow * 40 + sg * 8) = b0;
    *(bf16x8*)(Bs + (srow + 64) * 40 + sg * 8) = b1;
    __syncthreads();
    bf16x8 af[4], bfr[4];
#pragma unroll
    for (int mi = 0; mi < 4; mi++)
      af[mi] = *(const bf16x8*)(As + (wm * 64 + mi * 16 + li) * 40 + g * 8);
#pragma unroll
    for (int ni = 0; ni < 4; ni++)
      bfr[ni] = *(const bf16x8*)(Bs + (wn * 64 + ni * 16 + li) * 40 + g * 8);
#pragma unroll
    for (int mi = 0; mi < 4; mi++)
#pragma unroll
      for (int ni = 0; ni < 4; ni++)
        acc[mi][ni] = __builtin_amdgcn_mfma_f32_16x16x32_bf16(af[mi], bfr[ni], acc[mi][ni], 0, 0, 0);
  }

  if (MODE == 0) {
    const int sec = n0 >> 8;  // tile never crosses q/k/v section boundaries
    unsigned short* dst = (sec == 0) ? q_ws : ((sec == 1) ? k_ws : v_ws);
    const float qscale = 0.0625f * INV_LN2;   // SCALE * 1/ln2 folded into q
#pragma unroll
    for (int mi = 0; mi < 4; mi++)
#pragma unroll
      for (int ni = 0; ni < 4; ni++)
#pragma unroll
        for (int i = 0; i < 4; i++) {
          int m = m0 + wm * 64 + mi * 16 + g * 4 + i;
          int n = n0 + wn * 64 + ni * 16 + li;
          float val = acc[mi][ni][i] + bias[n];
          if (sec == 0) val *= qscale;
          int h = (n >> 5) & 7, d = n & 31;
          int b = m >> 10, s = m & 1023;
          dst[((long)(b * 8 + h) * 1024 + s) * 32 + d] = f2bf(val);
        }
  } else {
#pragma unroll
    for (int mi = 0; mi < 4; mi++)
#pragma unroll
      for (int ni = 0; ni < 4; ni++)
#pragma unroll
        for (int i = 0; i < 4; i++) {
          int m = m0 + wm * 64 + mi * 16 + g * 4 + i;
          int n = n0 + wn * 64 + ni * 16 + li;
          out[(long)m * 256 + n] = acc[mi][ni][i] + bias[n];
        }
  }
}

// ---------------- V transpose: [bh][s][32] -> [bh][32][s] ----------------
// 128 bh * 1024 s * 4 chunks = 524288 threads exactly (2048 blocks).
__global__ __launch_bounds__(256) void vtrans_kernel(
    const unsigned short* __restrict__ v, unsigned short* __restrict__ vt) {
  long u = (long)blockIdx.x * 256 + threadIdx.x;
  if (u >= 524288) return;                         // guard: never write OOB
  int tok_lin = (int)(u >> 2);                     // bh*1024 + s, < 131072
  int dchunk = ((int)u & 3) * 8;
  int bh = tok_lin >> 10, s = tok_lin & 1023;
  bf16x8 r = *(const bf16x8*)(v + (long)tok_lin * 32 + dchunk);
  unsigned short* base = vt + (long)bh * 32768 + s;
#pragma unroll
  for (int j = 0; j < 8; j++) base[(long)(dchunk + j) * 1024] = (unsigned short)r[j];
}

// ---------------- fused attention ----------------
// grid (16 q-tiles, 128 bh); 4 waves/WG, each wave owns 16 q rows.
// p = exp2(mfma(q*SCALE*IL2, k, C=bias_l2)); row sums via ones-column MFMA;
// O normalized at the end.
__global__ __launch_bounds__(256) void attn_kernel(
    const unsigned short* __restrict__ q_ws, const unsigned short* __restrict__ k_ws,
    const unsigned short* __restrict__ vt_ws, const unsigned short* __restrict__ biasb,
    unsigned short* __restrict__ attno) {
  __shared__ __align__(16) unsigned short Ks[64 * 40];    // [tok][d], pad 40
  __shared__ __align__(16) unsigned short Vt[32 * 72];    // [d][tok], pad 72
  __shared__ __align__(16) unsigned short Bi[64 * 72];    // [qrow][tok], pad 72
  __shared__ __align__(16) unsigned short Ps[4][16 * 72]; // per-wave P [16 q][tok]
  const int tid = threadIdx.x;
  const int lane = tid & 63, wid = tid >> 6;
  const int li = lane & 15, g = lane >> 4;
  const int bh = blockIdx.y;
  const int qblk = blockIdx.x * 64;
  const int q0 = qblk + wid * 16;
  const unsigned short* qb = q_ws + (long)bh * 32768;
  const unsigned short* kb = k_ws + (long)bh * 32768;
  const unsigned short* vb = vt_ws + (long)bh * 32768;

  // Q fragment: A[m=li (q row)][k=g*8.. (head dim)]
  bf16x8 qf = *(const bf16x8*)(qb + (q0 + li) * 32 + g * 8);

  // ones B-fragment: B[n=0][k]=1.0 -> col 0 of C accumulates row sums
  bf16x8 onesf = {};
  if (li == 0) {
#pragma unroll
    for (int j = 0; j < 8; j++) onesf[j] = (short)0x3F80;
  }

  f32x4 o0 = {}, o1 = {}, o2 = {};
  const int kt = tid >> 2, kd = (tid & 3) * 8;     // K staging
  const int vd = tid >> 3, vs = (tid & 7) * 8;     // V staging
  const int bq = tid >> 2, bt = (tid & 3) * 16;    // bias staging (2x b128)
  unsigned short* Pw = Ps[wid];

  for (int kv0 = 0; kv0 < 1024; kv0 += 64) {
    bf16x8 kv8 = *(const bf16x8*)(kb + (kv0 + kt) * 32 + kd);
    bf16x8 vv8 = *(const bf16x8*)(vb + vd * 1024 + kv0 + vs);
    bf16x8 bb0 = *(const bf16x8*)(biasb + (long)(qblk + bq) * 1024 + kv0 + bt);
    bf16x8 bb1 = *(const bf16x8*)(biasb + (long)(qblk + bq) * 1024 + kv0 + bt + 8);
    __syncthreads();  // previous iteration's LDS reads complete
    *(bf16x8*)(Ks + kt * 40 + kd) = kv8;
    *(bf16x8*)(Vt + vd * 72 + vs) = vv8;
    *(bf16x8*)(Bi + bq * 72 + bt) = bb0;
    *(bf16x8*)(Bi + bq * 72 + bt + 8) = bb1;
    __syncthreads();

    // QK^T with bias-in-log2 as accumulator init
    f32x4 sc[4];
#pragma unroll
    for (int c = 0; c < 4; c++) {
      const unsigned short* brow = Bi + (wid * 16 + g * 4) * 72 + c * 16 + li;
      f32x4 ci;
      ci[0] = bf2f(brow[0]);
      ci[1] = bf2f(brow[72]);
      ci[2] = bf2f(brow[144]);
      ci[3] = bf2f(brow[216]);
      bf16x8 kf = *(const bf16x8*)(Ks + (c * 16 + li) * 40 + g * 8);
      sc[c] = __builtin_amdgcn_mfma_f32_16x16x32_bf16(qf, kf, ci, 0, 0, 0);
    }

    // p = exp2(s); pack pairs with v_cvt_pk_bf16_f32, store to Ps rows
#pragma unroll
    for (int c = 0; c < 4; c++) {
      float p0 = exp2f(sc[c][0]);
      float p1 = exp2f(sc[c][1]);
      float p2 = exp2f(sc[c][2]);
      float p3 = exp2f(sc[c][3]);
      unsigned r01, r23;
      asm("v_cvt_pk_bf16_f32 %0, %1, %2" : "=v"(r01) : "v"(p0), "v"(p1));
      asm("v_cvt_pk_bf16_f32 %0, %1, %2" : "=v"(r23) : "v"(p2), "v"(p3));
      unsigned short* pb = Pw + (g * 4) * 72 + c * 16 + li;
      pb[0]   = (unsigned short)(r01 & 0xffffu);
      pb[72]  = (unsigned short)(r01 >> 16);
      pb[144] = (unsigned short)(r23 & 0xffffu);
      pb[216] = (unsigned short)(r23 >> 16);
    }

    // PV + ones-column row-sum MFMA
#pragma unroll
    for (int c2 = 0; c2 < 2; c2++) {
      bf16x8 pa  = *(const bf16x8*)(Pw + li * 72 + c2 * 32 + g * 8);
      bf16x8 vf0 = *(const bf16x8*)(Vt + li * 72 + c2 * 32 + g * 8);
      bf16x8 vf1 = *(const bf16x8*)(Vt + (li + 16) * 72 + c2 * 32 + g * 8);
      o0 = __builtin_amdgcn_mfma_f32_16x16x32_bf16(pa, vf0, o0, 0, 0, 0);
      o1 = __builtin_amdgcn_mfma_f32_16x16x32_bf16(pa, vf1, o1, 0, 0, 0);
      o2 = __builtin_amdgcn_mfma_f32_16x16x32_bf16(pa, onesf, o2, 0, 0, 0);
    }
  }

  const int b = bh >> 3, h = bh & 7;
#pragma unroll
  for (int i = 0; i < 4; i++) {
    float s = __shfl(o2[i], lane & 48, 64);  // broadcast row sum from lane li==0
    float inv = 1.0f / s;
    int srow = q0 + g * 4 + i;
    long base = ((long)(b * 1024 + srow)) * 256 + h * 32;
    attno[base + li] = f2bf(o0[i] * inv);
    attno[base + 16 + li] = f2bf(o1[i] * inv);
  }
}

// ---------------- launch ----------------
extern "C" void kernel_launch(void* const* d_in, const int* in_sizes, int n_in,
                              void* d_out, int out_size, void* d_ws, size_t ws_size,
                              hipStream_t stream) {
  const float* x      = (const float*)d_in[0];
  const float* wqkv   = (const float*)d_in[1];
  const float* bqkv   = (const float*)d_in[2];
  const float* wmerge = (const float*)d_in[3];
  const float* bmerge = (const float*)d_in[4];
  const float* rtab   = (const float*)d_in[5];
  const int*   ridx   = (const int*)d_in[6];
  float* out = (float*)d_out;

  char* ws = (char*)d_ws;
  unsigned short* xb    = (unsigned short*)(ws);                    //  8 MB (dead after gemm<0>)
  unsigned short* wqb   = (unsigned short*)(ws + 8388608);          // 384 KB
  unsigned short* wmb   = (unsigned short*)(ws + 8781824);          // 128 KB
  unsigned short* biasb = (unsigned short*)(ws + 8912896);          //  2 MB
  unsigned short* q_ws  = (unsigned short*)(ws + 11010048);         //  8 MB
  unsigned short* k_ws  = (unsigned short*)(ws + 19398656);         //  8 MB
  unsigned short* v_ws  = (unsigned short*)(ws + 27787264);         //  8 MB
  unsigned short* attno = (unsigned short*)(ws + 36175872);         //  8 MB
  unsigned short* vt_ws = xb;                                       // reuse xb region

  prep_kernel<<<5376, 256, 0, stream>>>(x, wqkv, wmerge, rtab, ridx, xb, wqb, wmb, biasb);
  gemm_k<0><<<dim3(6, 128), 256, 0, stream>>>(xb, wqb, bqkv, q_ws, k_ws, v_ws, nullptr);
  vtrans_kernel<<<2048, 256, 0, stream>>>(v_ws, vt_ws);
  attn_kernel<<<dim3(16, 128), 256, 0, stream>>>(q_ws, k_ws, vt_ws, biasb, attno);
  gemm_k<1><<<dim3(2, 128), 256, 0, stream>>>(attno, wmb, bmerge, nullptr, nullptr, nullptr, out);
}

// Round 4
// 114.264 us; speedup vs baseline: 1.0271x; 1.0271x over previous
//
#include <hip/hip_runtime.h>

// RelativeMultiHeadSelfAttention: B=16, S=1024, C=256, H=8 heads, D=32 head_dim
// prep (casts + bias gather *INV_LN2) -> QKV GEMM (bf16 MFMA, q scaled by
// SCALE*INV_LN2, V written transposed [bh][d][s]) -> fused attention
// (SWAPPED QK^T: mfma(K,Q) so lanes hold consecutive-token P; bias C-init via
// global b64; P via packed ds_write_b64; ones-MFMA row sums) -> merge GEMM.

typedef __attribute__((ext_vector_type(8))) short bf16x8;
typedef __attribute__((ext_vector_type(4))) float f32x4;

#define INV_LN2 1.44269504088896340736f

__device__ __forceinline__ unsigned short f2bf(float f) {
  union { float f; unsigned u; } v; v.f = f;
  unsigned r = v.u + 0x7fffu + ((v.u >> 16) & 1u);   // RNE
  return (unsigned short)(r >> 16);
}
__device__ __forceinline__ float u2f(unsigned u) {
  union { unsigned u; float f; } v; v.u = u;
  return v.f;
}

// ---------------- prep: casts + bias gather ----------------
__global__ __launch_bounds__(256) void prep_kernel(
    const float* __restrict__ x, const float* __restrict__ wq,
    const float* __restrict__ wm, const float* __restrict__ tab,
    const int* __restrict__ idx,
    unsigned short* __restrict__ xb, unsigned short* __restrict__ wqb,
    unsigned short* __restrict__ wmb, unsigned short* __restrict__ biasb) {
  const long NX = 1048576, NW1 = 49152, NW2 = 16384, NB = 262144;
  long u = (long)blockIdx.x * 256 + threadIdx.x;
  if (u < NX) {
    float4 v = ((const float4*)x)[u];
    ushort4 o; o.x = f2bf(v.x); o.y = f2bf(v.y); o.z = f2bf(v.z); o.w = f2bf(v.w);
    ((ushort4*)xb)[u] = o;
  } else if (u < NX + NW1) {
    long t = u - NX;
    float4 v = ((const float4*)wq)[t];
    ushort4 o; o.x = f2bf(v.x); o.y = f2bf(v.y); o.z = f2bf(v.z); o.w = f2bf(v.w);
    ((ushort4*)wqb)[t] = o;
  } else if (u < NX + NW1 + NW2) {
    long t = u - NX - NW1;
    float4 v = ((const float4*)wm)[t];
    ushort4 o; o.x = f2bf(v.x); o.y = f2bf(v.y); o.z = f2bf(v.z); o.w = f2bf(v.w);
    ((ushort4*)wmb)[t] = o;
  } else if (u < NX + NW1 + NW2 + NB) {
    long t = u - NX - NW1 - NW2;
    int4 iv = ((const int4*)idx)[t];
    ushort4 o;
    o.x = f2bf(tab[(long)iv.x * 8] * INV_LN2);
    o.y = f2bf(tab[(long)iv.y * 8] * INV_LN2);
    o.z = f2bf(tab[(long)iv.z * 8] * INV_LN2);
    o.w = f2bf(tab[(long)iv.w * 8] * INV_LN2);
    ((ushort4*)biasb)[t] = o;
  }
}

// ---------------- GEMM (QKV / merge) ----------------
// C[m,n] = sum_k A[m,k]*Bw[n,k] (+ bias[n]); padded LDS [128][40].
// MODE 0: q/k -> [bh][s][32]; V -> TRANSPOSED [bh][d][1024]. MODE 1: f32 out.
template <int MODE>
__global__ __launch_bounds__(256) void gemm_k(
    const unsigned short* __restrict__ A, const unsigned short* __restrict__ Bw,
    const float* __restrict__ bias,
    unsigned short* __restrict__ q_ws, unsigned short* __restrict__ k_ws,
    unsigned short* __restrict__ v_ws, float* __restrict__ out) {
  __shared__ __align__(16) unsigned short As[128 * 40];
  __shared__ __align__(16) unsigned short Bs[128 * 40];
  const int tid = threadIdx.x;
  const int lane = tid & 63, wid = tid >> 6;
  const int wm = wid >> 1, wn = wid & 1;
  const int li = lane & 15, g = lane >> 4;
  const int m0 = blockIdx.y * 128;
  const int n0 = blockIdx.x * 128;
  f32x4 acc[4][4] = {};
  const int srow = tid >> 2, sg = tid & 3;
  const unsigned short* Ag = A + (long)(m0 + srow) * 256 + sg * 8;
  const unsigned short* Bg = Bw + (long)(n0 + srow) * 256 + sg * 8;

  for (int kt = 0; kt < 8; ++kt) {
    const int k0 = kt * 32;
    bf16x8 a0 = *(const bf16x8*)(Ag + k0);
    bf16x8 a1 = *(const bf16x8*)(Ag + 64 * 256 + k0);
    bf16x8 b0 = *(const bf16x8*)(Bg + k0);
    bf16x8 b1 = *(const bf16x8*)(Bg + 64 * 256 + k0);
    __syncthreads();
    *(bf16x8*)(As + srow * 40 + sg * 8) = a0;
    *(bf16x8*)(As + (srow + 64) * 40 + sg * 8) = a1;
    *(bf16x8*)(Bs + srow * 40 + sg * 8) = b0;
    *(bf16x8*)(Bs + (srow + 64) * 40 + sg * 8) = b1;
    __syncthreads();
    bf16x8 af[4], bfr[4];
#pragma unroll
    for (int mi = 0; mi < 4; mi++)
      af[mi] = *(const bf16x8*)(As + (wm * 64 + mi * 16 + li) * 40 + g * 8);
#pragma unroll
    for (int ni = 0; ni < 4; ni++)
      bfr[ni] = *(const bf16x8*)(Bs + (wn * 64 + ni * 16 + li) * 40 + g * 8);
#pragma unroll
    for (int mi = 0; mi < 4; mi++)
#pragma unroll
      for (int ni = 0; ni < 4; ni++)
        acc[mi][ni] = __builtin_amdgcn_mfma_f32_16x16x32_bf16(af[mi], bfr[ni], acc[mi][ni], 0, 0, 0);
  }

  if (MODE == 0) {
    const int sec = n0 >> 8;  // tile never crosses q/k/v section boundaries
    unsigned short* dst = (sec == 0) ? q_ws : k_ws;
    const float qscale = 0.0625f * INV_LN2;   // SCALE * 1/ln2 folded into q
#pragma unroll
    for (int mi = 0; mi < 4; mi++)
#pragma unroll
      for (int ni = 0; ni < 4; ni++)
#pragma unroll
        for (int i = 0; i < 4; i++) {
          int m = m0 + wm * 64 + mi * 16 + g * 4 + i;
          int n = n0 + wn * 64 + ni * 16 + li;
          float val = acc[mi][ni][i] + bias[n];
          if (sec == 0) val *= qscale;
          int h = (n >> 5) & 7, d = n & 31;
          int b = m >> 10, s = m & 1023;
          if (sec == 2)
            v_ws[(long)(b * 8 + h) * 32768 + (long)d * 1024 + s] = f2bf(val);
          else
            dst[((long)(b * 8 + h) * 1024 + s) * 32 + d] = f2bf(val);
        }
  } else {
#pragma unroll
    for (int mi = 0; mi < 4; mi++)
#pragma unroll
      for (int ni = 0; ni < 4; ni++)
#pragma unroll
        for (int i = 0; i < 4; i++) {
          int m = m0 + wm * 64 + mi * 16 + g * 4 + i;
          int n = n0 + wn * 64 + ni * 16 + li;
          out[(long)m * 256 + n] = acc[mi][ni][i] + bias[n];
        }
  }
}

// ---------------- fused attention (swapped QK^T) ----------------
// grid (16 q-tiles, 128 bh); 4 waves/WG, each wave owns 16 q rows.
// sc = mfma(K, Q, C=bias_l2) -> D[m=tok][n=q]: lane (li,g) reg i holds
// P_pre[tok=16c+4g+i][q=li]. p = exp2(sc); packed pairs -> ds_write_b64 into
// Ps[q][tok]; PV reads b128 A-frags. Row sums via ones-column MFMA.
__global__ __launch_bounds__(256) void attn_kernel(
    const unsigned short* __restrict__ q_ws, const unsigned short* __restrict__ k_ws,
    const unsigned short* __restrict__ vt_ws, const unsigned short* __restrict__ biasb,
    unsigned short* __restrict__ attno) {
  __shared__ __align__(16) unsigned short Ks[64 * 40];    // [tok][d]
  __shared__ __align__(16) unsigned short Vt[32 * 72];    // [d][tok]
  __shared__ __align__(16) unsigned short Ps[4][16 * 72]; // per-wave [q][tok]
  const int tid = threadIdx.x;
  const int lane = tid & 63, wid = tid >> 6;
  const int li = lane & 15, g = lane >> 4;
  const int bh = blockIdx.y;
  const int qblk = blockIdx.x * 64;
  const int q0 = qblk + wid * 16;
  const unsigned short* qb = q_ws + (long)bh * 32768;
  const unsigned short* kb = k_ws + (long)bh * 32768;
  const unsigned short* vb = vt_ws + (long)bh * 32768;
  const unsigned short* bias_row = biasb + (long)(q0 + li) * 1024;  // this lane's q row

  // Q as B-fragment: B[n=li (q)][k=g*8.. (d)]
  bf16x8 qf = *(const bf16x8*)(qb + (q0 + li) * 32 + g * 8);

  // ones B-fragment: B[n=0][k]=1.0 -> col 0 accumulates row sums
  bf16x8 onesf = {};
  if (li == 0) {
#pragma unroll
    for (int j = 0; j < 8; j++) onesf[j] = (short)0x3F80;
  }

  f32x4 o0 = {}, o1 = {}, o2 = {};
  const int kt = tid >> 2, kd = (tid & 3) * 8;     // K staging
  const int vd = tid >> 3, vs = (tid & 7) * 8;     // V staging
  unsigned short* Pw = Ps[wid];

  for (int kv0 = 0; kv0 < 1024; kv0 += 64) {
    bf16x8 kv8 = *(const bf16x8*)(kb + (kv0 + kt) * 32 + kd);
    bf16x8 vv8 = *(const bf16x8*)(vb + vd * 1024 + kv0 + vs);
    __syncthreads();  // previous iteration's Ks/Vt reads complete
    *(bf16x8*)(Ks + kt * 40 + kd) = kv8;
    *(bf16x8*)(Vt + vd * 72 + vs) = vv8;
    __syncthreads();

    // swapped QK^T: sc[c] = mfma(A=K, B=Q, C=bias);  bias from global (L2-hot)
    f32x4 sc[4];
#pragma unroll
    for (int c = 0; c < 4; c++) {
      uint2 bd = *(const uint2*)(bias_row + kv0 + c * 16 + g * 4);
      f32x4 ci;
      ci[0] = u2f(bd.x << 16);
      ci[1] = u2f(bd.x & 0xffff0000u);
      ci[2] = u2f(bd.y << 16);
      ci[3] = u2f(bd.y & 0xffff0000u);
      bf16x8 kf = *(const bf16x8*)(Ks + (c * 16 + li) * 40 + g * 8);
      sc[c] = __builtin_amdgcn_mfma_f32_16x16x32_bf16(kf, qf, ci, 0, 0, 0);
    }

    // p = exp2(sc) (raw v_exp_f32); pack pairs (consecutive toks) -> b64 store
#pragma unroll
    for (int c = 0; c < 4; c++) {
      float p0 = __builtin_amdgcn_exp2f(sc[c][0]);
      float p1 = __builtin_amdgcn_exp2f(sc[c][1]);
      float p2 = __builtin_amdgcn_exp2f(sc[c][2]);
      float p3 = __builtin_amdgcn_exp2f(sc[c][3]);
      unsigned r01, r23;
      asm("v_cvt_pk_bf16_f32 %0, %1, %2" : "=v"(r01) : "v"(p0), "v"(p1));
      asm("v_cvt_pk_bf16_f32 %0, %1, %2" : "=v"(r23) : "v"(p2), "v"(p3));
      uint2 pk; pk.x = r01; pk.y = r23;
      *(uint2*)(Pw + li * 72 + c * 16 + g * 4) = pk;   // toks 16c+4g..+3, q=li
    }

    // PV + ones-column row-sum MFMA (Ps is per-wave: no barrier needed)
#pragma unroll
    for (int c2 = 0; c2 < 2; c2++) {
      bf16x8 pa  = *(const bf16x8*)(Pw + li * 72 + c2 * 32 + g * 8);
      bf16x8 vf0 = *(const bf16x8*)(Vt + li * 72 + c2 * 32 + g * 8);
      bf16x8 vf1 = *(const bf16x8*)(Vt + (li + 16) * 72 + c2 * 32 + g * 8);
      o0 = __builtin_amdgcn_mfma_f32_16x16x32_bf16(pa, vf0, o0, 0, 0, 0);
      o1 = __builtin_amdgcn_mfma_f32_16x16x32_bf16(pa, vf1, o1, 0, 0, 0);
      o2 = __builtin_amdgcn_mfma_f32_16x16x32_bf16(pa, onesf, o2, 0, 0, 0);
    }
  }

  const int b = bh >> 3, h = bh & 7;
#pragma unroll
  for (int i = 0; i < 4; i++) {
    float s = __shfl(o2[i], lane & 48, 64);  // row sum lives at li==0 lane of this g
    float inv = 1.0f / s;
    int srow = q0 + g * 4 + i;
    long base = ((long)(b * 1024 + srow)) * 256 + h * 32;
    attno[base + li] = f2bf(o0[i] * inv);
    attno[base + 16 + li] = f2bf(o1[i] * inv);
  }
}

// ---------------- launch ----------------
extern "C" void kernel_launch(void* const* d_in, const int* in_sizes, int n_in,
                              void* d_out, int out_size, void* d_ws, size_t ws_size,
                              hipStream_t stream) {
  const float* x      = (const float*)d_in[0];
  const float* wqkv   = (const float*)d_in[1];
  const float* bqkv   = (const float*)d_in[2];
  const float* wmerge = (const float*)d_in[3];
  const float* bmerge = (const float*)d_in[4];
  const float* rtab   = (const float*)d_in[5];
  const int*   ridx   = (const int*)d_in[6];
  float* out = (float*)d_out;

  char* ws = (char*)d_ws;
  unsigned short* xb    = (unsigned short*)(ws);                    //  8 MB
  unsigned short* wqb   = (unsigned short*)(ws + 8388608);          // 384 KB
  unsigned short* wmb   = (unsigned short*)(ws + 8781824);          // 128 KB
  unsigned short* biasb = (unsigned short*)(ws + 8912896);          //  2 MB
  unsigned short* q_ws  = (unsigned short*)(ws + 11010048);         //  8 MB
  unsigned short* k_ws  = (unsigned short*)(ws + 19398656);         //  8 MB
  unsigned short* v_ws  = (unsigned short*)(ws + 27787264);         //  8 MB (transposed [bh][d][s])
  unsigned short* attno = (unsigned short*)(ws + 36175872);         //  8 MB

  prep_kernel<<<5376, 256, 0, stream>>>(x, wqkv, wmerge, rtab, ridx, xb, wqb, wmb, biasb);
  gemm_k<0><<<dim3(6, 128), 256, 0, stream>>>(xb, wqb, bqkv, q_ws, k_ws, v_ws, nullptr);
  attn_kernel<<<dim3(16, 128), 256, 0, stream>>>(q_ws, k_ws, v_ws, biasb, attno);
  gemm_k<1><<<dim3(2, 128), 256, 0, stream>>>(attno, wmb, bmerge, nullptr, nullptr, nullptr, out);
}